// Round 2
// baseline (415.252 us; speedup 1.0000x reference)
//
#include <hip/hip_runtime.h>
#include <stdint.h>
#include <stddef.h>

typedef __attribute__((ext_vector_type(8))) short bf16x8_t;
typedef __attribute__((ext_vector_type(4))) float f32x4_t;

__device__ __forceinline__ unsigned short f2bf(float f) {
  union { float f; unsigned int u; } x; x.f = f;
  unsigned int r = x.u + 0x7fffu + ((x.u >> 16) & 1u);
  return (unsigned short)(r >> 16);
}

// async global->LDS, 16B per lane; LDS dest = wave-uniform base + lane*16
__device__ __forceinline__ void gload16(const void* g, void* l) {
  __builtin_amdgcn_global_load_lds(
      (const __attribute__((address_space(1))) void*)g,
      (__attribute__((address_space(3))) void*)l, 16, 0, 0);
}

// ---------------------------------------------------------------------------
// x: f32 -> bf16, 8 elems/thread
// ---------------------------------------------------------------------------
__global__ __launch_bounds__(256)
void f32_to_bf16(const float* __restrict__ in, unsigned short* __restrict__ out) {
  size_t i = ((size_t)blockIdx.x * 256 + threadIdx.x) * 8;
  f32x4_t a = *(const f32x4_t*)(in + i);
  f32x4_t b = *(const f32x4_t*)(in + i + 4);
  bf16x8_t o;
#pragma unroll
  for (int j = 0; j < 4; ++j) { o[j] = (short)f2bf(a[j]); o[j + 4] = (short)f2bf(b[j]); }
  *(bf16x8_t*)(out + i) = o;
}

// ---------------------------------------------------------------------------
// weight f32 [1024][1024] -> bf16 transposed [1024][1024]
// ---------------------------------------------------------------------------
__global__ __launch_bounds__(256)
void transpose_cvt(const float* __restrict__ in, unsigned short* __restrict__ out) {
  __shared__ float t[32][33];
  const int x = threadIdx.x & 31, y = threadIdx.x >> 5;  // 32 x 8
  const int bx = blockIdx.x * 32, by = blockIdx.y * 32;
#pragma unroll
  for (int i = 0; i < 32; i += 8)
    t[y + i][x] = in[(size_t)(by + y + i) * 1024 + bx + x];
  __syncthreads();
#pragma unroll
  for (int i = 0; i < 32; i += 8)
    out[(size_t)(bx + y + i) * 1024 + by + x] = f2bf(t[x][y + i]);
}

// ---------------------------------------------------------------------------
// v bf16 [bh][2048][64] -> vt bf16 [bh][64][2048]
// ---------------------------------------------------------------------------
__global__ __launch_bounds__(256)
void transpose_v(const unsigned short* __restrict__ in, unsigned short* __restrict__ out) {
  __shared__ unsigned short t[64][65];
  const int bh = blockIdx.y;
  const int n0 = blockIdx.x * 64;
  const int c = threadIdx.x & 63, r4 = threadIdx.x >> 6;  // 64 x 4
#pragma unroll
  for (int i = 0; i < 64; i += 4)
    t[r4 + i][c] = in[((size_t)bh * 2048 + n0 + r4 + i) * 64 + c];
  __syncthreads();
#pragma unroll
  for (int i = 0; i < 64; i += 4)
    out[((size_t)bh * 64 + r4 + i) * 2048 + n0 + c] = t[c][r4 + i];
}

// ---------------------------------------------------------------------------
// 128x128-tile bf16 MFMA GEMM: C = A[M][K] * Bt[Nn][K]^T
// MODE 0: bf16 scatter [b,h,n,hd], scaled by 0.125   (Q)
// MODE 1: bf16 scatter [b,h,n,hd]                    (K, V)
// MODE 2: f32 [row][col] + f32 bias                  (output projection)
// ---------------------------------------------------------------------------
template <int MODE>
__global__ __launch_bounds__(256, 2)
void gemm128(const unsigned short* __restrict__ A,
             const unsigned short* __restrict__ Bt,
             void* __restrict__ Cv,
             const float* __restrict__ bias,
             int M, int K, int Nn) {
  constexpr int BK = 32;
  __shared__ __align__(16) unsigned short As[128 * BK];
  __shared__ __align__(16) unsigned short Bs[128 * BK];

  const int tid = threadIdx.x;
  const int wave = tid >> 6;
  const int lane = tid & 63;
  const int l15 = lane & 15;
  const int lq = lane >> 4;
  const int row0 = blockIdx.x * 128;
  const int col0 = blockIdx.y * 128;
  const int wr = (wave >> 1) * 64;
  const int wc = (wave & 1) * 64;

  f32x4_t acc[4][4];
#pragma unroll
  for (int m = 0; m < 4; ++m)
#pragma unroll
    for (int n = 0; n < 4; ++n) acc[m][n] = (f32x4_t)0.f;

  // 512 16B chunks/tile; thread stages chunks tid and tid+256.
  // chunk p: row=p>>2, phys slot=p&3, logical slot=(p&3)^(row&3)
  const int p0 = tid, p1 = tid + 256;
  const int pr0 = p0 >> 2, ps0 = (p0 & 3) ^ (pr0 & 3);
  const int pr1 = p1 >> 2, ps1 = (p1 & 3) ^ (pr1 & 3);

  char* As0 = (char*)As + wave * 1024;
  char* As1 = (char*)As + 4096 + wave * 1024;
  char* Bs0 = (char*)Bs + wave * 1024;
  char* Bs1 = (char*)Bs + 4096 + wave * 1024;

  const unsigned short* Ap0 = A + (size_t)(row0 + pr0) * K + ps0 * 8;
  const unsigned short* Ap1 = A + (size_t)(row0 + pr1) * K + ps1 * 8;
  const unsigned short* Bp0 = Bt + (size_t)(col0 + pr0) * K + ps0 * 8;
  const unsigned short* Bp1 = Bt + (size_t)(col0 + pr1) * K + ps1 * 8;

  for (int k0 = 0; k0 < K; k0 += BK) {
    __syncthreads();
    gload16(Ap0 + k0, As0);
    gload16(Ap1 + k0, As1);
    gload16(Bp0 + k0, Bs0);
    gload16(Bp1 + k0, Bs1);
    __syncthreads();

    bf16x8_t af[4], bfr[4];
#pragma unroll
    for (int m = 0; m < 4; ++m) {
      int r = wr + m * 16 + l15;
      af[m] = *(const bf16x8_t*)((const char*)As + r * 64 + ((lq ^ (r & 3)) << 4));
    }
#pragma unroll
    for (int n = 0; n < 4; ++n) {
      int c = wc + n * 16 + l15;
      bfr[n] = *(const bf16x8_t*)((const char*)Bs + c * 64 + ((lq ^ (c & 3)) << 4));
    }
#pragma unroll
    for (int m = 0; m < 4; ++m)
#pragma unroll
      for (int n = 0; n < 4; ++n)
        acc[m][n] = __builtin_amdgcn_mfma_f32_16x16x32_bf16(af[m], bfr[n], acc[m][n], 0, 0, 0);
  }

  // C/D layout: col = lane&15, row = (lane>>4)*4 + j  (m89-verified)
#pragma unroll
  for (int m = 0; m < 4; ++m) {
    int rb = row0 + wr + m * 16 + lq * 4;
#pragma unroll
    for (int n = 0; n < 4; ++n) {
      int col = col0 + wc + n * 16 + l15;
#pragma unroll
      for (int j = 0; j < 4; ++j) {
        int row = rb + j;
        float v = acc[m][n][j];
        if constexpr (MODE == 0) {
          int b = row >> 11, nn = row & 2047, h = col >> 6, hd = col & 63;
          ((unsigned short*)Cv)[(((size_t)(b * 16 + h)) * 2048 + nn) * 64 + hd] = f2bf(v * 0.125f);
        } else if constexpr (MODE == 1) {
          int b = row >> 11, nn = row & 2047, h = col >> 6, hd = col & 63;
          ((unsigned short*)Cv)[(((size_t)(b * 16 + h)) * 2048 + nn) * 64 + hd] = f2bf(v);
        } else {
          ((float*)Cv)[(size_t)row * Nn + col] = v + bias[col];
        }
      }
    }
  }
}

// ---------------------------------------------------------------------------
// MFMA flash attention.
// qb (pre-scaled), kb: bf16 [bh][2048][64]; vtb: bf16 [bh][64][2048]
// Block: 256 thr = 4 waves; 64 Q rows/block (16/wave); KV tiles of 64.
// ---------------------------------------------------------------------------
__global__ __launch_bounds__(256, 2)
void attn_mfma(const unsigned short* __restrict__ qb,
               const unsigned short* __restrict__ kb,
               const unsigned short* __restrict__ vtb,
               unsigned short* __restrict__ ab) {
  __shared__ __align__(16) unsigned short Ks[4096];   // [key][hd] slot-swizzled
  __shared__ __align__(16) unsigned short Vs[4096];   // [hd][key] slot-swizzled
  __shared__ __align__(16) unsigned short Ps[4][1024];// per-wave [row][key] swizzled

  const int tid = threadIdx.x, wave = tid >> 6, lane = tid & 63;
  const int l15 = lane & 15, lq = lane >> 4;
  const int bh = blockIdx.y;
  const int q0 = blockIdx.x * 64;

  // Q fragments (2 k-steps), rows = q0 + wave*16 + l15
  const unsigned short* qptr = qb + ((size_t)bh * 2048 + q0 + wave * 16 + l15) * 64;
  bf16x8_t aq0 = *(const bf16x8_t*)(qptr + lq * 8);
  bf16x8_t aq1 = *(const bf16x8_t*)(qptr + 32 + lq * 8);

  f32x4_t O[4];
  float m_run[4], l_run[4];
#pragma unroll
  for (int n = 0; n < 4; ++n) O[n] = (f32x4_t)0.f;
#pragma unroll
  for (int j = 0; j < 4; ++j) { m_run[j] = -1e30f; l_run[j] = 0.f; }

  // staging: 512 chunks per 8KB tile; chunk p: row=p>>3, phys slot=p&7,
  // logical slot=(p&7)^(row&7)
  const int p0 = tid, p1 = tid + 256;
  const int r0 = p0 >> 3, s0 = (p0 & 7) ^ (r0 & 7);
  const int r1 = p1 >> 3, s1 = (p1 & 7) ^ (r1 & 7);

  const unsigned short* Kg0 = kb + ((size_t)bh * 2048 + r0) * 64 + s0 * 8;
  const unsigned short* Kg1 = kb + ((size_t)bh * 2048 + r1) * 64 + s1 * 8;
  const unsigned short* Vg0 = vtb + ((size_t)bh * 64 + r0) * 2048 + s0 * 8;
  const unsigned short* Vg1 = vtb + ((size_t)bh * 64 + r1) * 2048 + s1 * 8;

  char* kd0 = (char*)Ks + wave * 1024, *kd1 = (char*)Ks + 4096 + wave * 1024;
  char* vd0 = (char*)Vs + wave * 1024, *vd1 = (char*)Vs + 4096 + wave * 1024;

  for (int kv = 0; kv < 2048; kv += 64) {
    __syncthreads();
    gload16(Kg0 + (size_t)kv * 64, kd0);
    gload16(Kg1 + (size_t)kv * 64, kd1);
    gload16(Vg0 + kv, vd0);
    gload16(Vg1 + kv, vd1);
    __syncthreads();

    // S = Q K^T  (A rows = q, B cols = keys)
    f32x4_t sacc[4];
#pragma unroll
    for (int n = 0; n < 4; ++n) sacc[n] = (f32x4_t)0.f;
#pragma unroll
    for (int ks = 0; ks < 2; ++ks) {
      bf16x8_t aq = ks ? aq1 : aq0;
#pragma unroll
      for (int n = 0; n < 4; ++n) {
        int key = n * 16 + l15;
        bf16x8_t kf = *(const bf16x8_t*)((const char*)Ks + key * 128 +
                                         (((ks * 4 + lq) ^ (key & 7)) << 4));
        sacc[n] = __builtin_amdgcn_mfma_f32_16x16x32_bf16(aq, kf, sacc[n], 0, 0, 0);
      }
    }

    // online softmax; lane element j is q-row lq*4+j
    float mnew[4];
#pragma unroll
    for (int j = 0; j < 4; ++j)
      mnew[j] = fmaxf(fmaxf(sacc[0][j], sacc[1][j]), fmaxf(sacc[2][j], sacc[3][j]));
#pragma unroll
    for (int mask = 1; mask <= 8; mask <<= 1)
#pragma unroll
      for (int j = 0; j < 4; ++j) mnew[j] = fmaxf(mnew[j], __shfl_xor(mnew[j], mask));

    float alpha[4], psum[4];
#pragma unroll
    for (int j = 0; j < 4; ++j) {
      float mn = fmaxf(m_run[j], mnew[j]);
      alpha[j] = __expf(m_run[j] - mn);
      m_run[j] = mn;
      psum[j] = 0.f;
    }
    unsigned short pb[4][4];
#pragma unroll
    for (int n = 0; n < 4; ++n)
#pragma unroll
      for (int j = 0; j < 4; ++j) {
        float p = __expf(sacc[n][j] - m_run[j]);
        psum[j] += p;
        pb[n][j] = f2bf(p);
      }
#pragma unroll
    for (int mask = 1; mask <= 8; mask <<= 1)
#pragma unroll
      for (int j = 0; j < 4; ++j) psum[j] += __shfl_xor(psum[j], mask);
#pragma unroll
    for (int j = 0; j < 4; ++j) l_run[j] = l_run[j] * alpha[j] + psum[j];
#pragma unroll
    for (int n = 0; n < 4; ++n)
#pragma unroll
      for (int j = 0; j < 4; ++j) O[n][j] *= alpha[j];

    // P -> LDS (transpose C-layout to A-frag layout)
    char* Pw = (char*)Ps[wave];
#pragma unroll
    for (int n = 0; n < 4; ++n)
#pragma unroll
      for (int j = 0; j < 4; ++j) {
        int row = lq * 4 + j, key = n * 16 + l15;
        *(unsigned short*)(Pw + row * 128 + (((key >> 3) ^ (row & 7)) << 4) +
                           (key & 7) * 2) = pb[n][j];
      }
    __syncthreads();  // order P write -> P read (safe, uniform)

    // O += P V
#pragma unroll
    for (int ks = 0; ks < 2; ++ks) {
      bf16x8_t pa = *(const bf16x8_t*)((const char*)Ps[wave] + l15 * 128 +
                                       (((ks * 4 + lq) ^ (l15 & 7)) << 4));
#pragma unroll
      for (int n = 0; n < 4; ++n) {
        int hd = n * 16 + l15;
        bf16x8_t vf = *(const bf16x8_t*)((const char*)Vs + hd * 128 +
                                         (((ks * 4 + lq) ^ (hd & 7)) << 4));
        O[n] = __builtin_amdgcn_mfma_f32_16x16x32_bf16(pa, vf, O[n], 0, 0, 0);
      }
    }
  }

  // epilogue: out row = q0 + wave*16 + lq*4 + j, hd = n*16 + l15
  const int b = bh >> 4, h = bh & 15;
#pragma unroll
  for (int j = 0; j < 4; ++j) {
    float inv = 1.f / l_run[j];
    int row = q0 + wave * 16 + lq * 4 + j;
#pragma unroll
    for (int n = 0; n < 4; ++n)
      ab[((size_t)(b * 2048 + row)) * 1024 + h * 64 + n * 16 + l15] = f2bf(O[n][j] * inv);
  }
}

// ---------------------------------------------------------------------------
extern "C" void kernel_launch(void* const* d_in, const int* in_sizes, int n_in,
                              void* d_out, int out_size, void* d_ws, size_t ws_size,
                              hipStream_t stream) {
  const float* x  = (const float*)d_in[0];
  const float* wq = (const float*)d_in[1];
  const float* wk = (const float*)d_in[2];
  const float* wv = (const float*)d_in[3];
  const float* wo = (const float*)d_in[4];
  const float* bo = (const float*)d_in[5];
  float* out = (float*)d_out;

  const size_t MB = 1ull << 20;
  char* ws = (char*)d_ws;
  unsigned short* xb  = (unsigned short*)(ws);            // 16.8 MB bf16 [8192][1024]
  unsigned short* ab  = xb;                               // reuse after x dead
  unsigned short* qb  = (unsigned short*)(ws + 17 * MB);  // bf16 [64][2048][64]
  unsigned short* kb  = (unsigned short*)(ws + 34 * MB);
  unsigned short* vb  = (unsigned short*)(ws + 51 * MB);
  unsigned short* vtb = (unsigned short*)(ws + 68 * MB);  // bf16 [64][64][2048]
  unsigned short* wqT = (unsigned short*)(ws + 85 * MB);  // 2 MB each
  unsigned short* wkT = (unsigned short*)(ws + 87 * MB);
  unsigned short* wvT = (unsigned short*)(ws + 89 * MB);
  unsigned short* woT = (unsigned short*)(ws + 91 * MB);

  const dim3 tb(256);
  f32_to_bf16<<<4096, tb, 0, stream>>>(x, xb);
  const dim3 tg(32, 32);
  transpose_cvt<<<tg, tb, 0, stream>>>(wq, wqT);
  transpose_cvt<<<tg, tb, 0, stream>>>(wk, wkT);
  transpose_cvt<<<tg, tb, 0, stream>>>(wv, wvT);
  transpose_cvt<<<tg, tb, 0, stream>>>(wo, woT);

  const dim3 gg(64, 8);  // M=8192, N=1024
  gemm128<0><<<gg, tb, 0, stream>>>(xb, wqT, (void*)qb, nullptr, 8192, 1024, 1024);
  gemm128<1><<<gg, tb, 0, stream>>>(xb, wkT, (void*)kb, nullptr, 8192, 1024, 1024);
  gemm128<1><<<gg, tb, 0, stream>>>(xb, wvT, (void*)vb, nullptr, 8192, 1024, 1024);

  transpose_v<<<dim3(32, 64), tb, 0, stream>>>(vb, vtb);

  attn_mfma<<<dim3(32, 64), tb, 0, stream>>>(qb, kb, vtb, ab);

  gemm128<2><<<gg, tb, 0, stream>>>(ab, woT, (void*)out, bo, 8192, 1024, 1024);
}

// Round 3
// 378.929 us; speedup vs baseline: 1.0959x; 1.0959x over previous
//
#include <hip/hip_runtime.h>
#include <stdint.h>
#include <stddef.h>

typedef __attribute__((ext_vector_type(8))) short bf16x8_t;
typedef __attribute__((ext_vector_type(4))) float f32x4_t;

__device__ __forceinline__ unsigned short f2bf(float f) {
  union { float f; unsigned int u; } x; x.f = f;
  unsigned int r = x.u + 0x7fffu + ((x.u >> 16) & 1u);
  return (unsigned short)(r >> 16);
}

__device__ __forceinline__ float e2(float x) { return __builtin_amdgcn_exp2f(x); }

// async global->LDS, 16B per lane; LDS dest = wave-uniform base + lane*16
__device__ __forceinline__ void gload16(const void* g, void* l) {
  __builtin_amdgcn_global_load_lds(
      (const __attribute__((address_space(1))) void*)g,
      (__attribute__((address_space(3))) void*)l, 16, 0, 0);
}

// qscale = 1/sqrt(64) * log2(e)  (exp2-domain softmax)
#define QSCALE 0.18033688011112042f

// ---------------------------------------------------------------------------
// x: f32 -> bf16, 8 elems/thread
// ---------------------------------------------------------------------------
__global__ __launch_bounds__(256)
void f32_to_bf16(const float* __restrict__ in, unsigned short* __restrict__ out) {
  size_t i = ((size_t)blockIdx.x * 256 + threadIdx.x) * 8;
  f32x4_t a = *(const f32x4_t*)(in + i);
  f32x4_t b = *(const f32x4_t*)(in + i + 4);
  bf16x8_t o;
#pragma unroll
  for (int j = 0; j < 4; ++j) { o[j] = (short)f2bf(a[j]); o[j + 4] = (short)f2bf(b[j]); }
  *(bf16x8_t*)(out + i) = o;
}

// ---------------------------------------------------------------------------
// 3 weights f32 [1024][1024] -> bf16 transposed, concatenated [3072][1024]
// ---------------------------------------------------------------------------
__global__ __launch_bounds__(256)
void transpose_cvt3(const float* __restrict__ w0, const float* __restrict__ w1,
                    const float* __restrict__ w2, unsigned short* __restrict__ out) {
  __shared__ float t[32][33];
  const float* in = blockIdx.z == 0 ? w0 : (blockIdx.z == 1 ? w1 : w2);
  unsigned short* o = out + (size_t)blockIdx.z * 1024 * 1024;
  const int x = threadIdx.x & 31, y = threadIdx.x >> 5;  // 32 x 8
  const int bx = blockIdx.x * 32, by = blockIdx.y * 32;
#pragma unroll
  for (int i = 0; i < 32; i += 8)
    t[y + i][x] = in[(size_t)(by + y + i) * 1024 + bx + x];
  __syncthreads();
#pragma unroll
  for (int i = 0; i < 32; i += 8)
    o[(size_t)(bx + y + i) * 1024 + by + x] = f2bf(t[x][y + i]);
}

__global__ __launch_bounds__(256)
void transpose_cvt(const float* __restrict__ in, unsigned short* __restrict__ out) {
  __shared__ float t[32][33];
  const int x = threadIdx.x & 31, y = threadIdx.x >> 5;
  const int bx = blockIdx.x * 32, by = blockIdx.y * 32;
#pragma unroll
  for (int i = 0; i < 32; i += 8)
    t[y + i][x] = in[(size_t)(by + y + i) * 1024 + bx + x];
  __syncthreads();
#pragma unroll
  for (int i = 0; i < 32; i += 8)
    out[(size_t)(bx + y + i) * 1024 + by + x] = f2bf(t[x][y + i]);
}

// ---------------------------------------------------------------------------
// v bf16 [bh][2048][64] -> vt bf16 [bh][64][2048]
// ---------------------------------------------------------------------------
__global__ __launch_bounds__(256)
void transpose_v(const unsigned short* __restrict__ in, unsigned short* __restrict__ out) {
  __shared__ unsigned short t[64][65];
  const int bh = blockIdx.y;
  const int n0 = blockIdx.x * 64;
  const int c = threadIdx.x & 63, r4 = threadIdx.x >> 6;  // 64 x 4
#pragma unroll
  for (int i = 0; i < 64; i += 4)
    t[r4 + i][c] = in[((size_t)bh * 2048 + n0 + r4 + i) * 64 + c];
  __syncthreads();
#pragma unroll
  for (int i = 0; i < 64; i += 4)
    out[((size_t)bh * 64 + r4 + i) * 2048 + n0 + c] = t[c][r4 + i];
}

// ---------------------------------------------------------------------------
// 128x128-tile bf16 MFMA GEMM: C = A[M][K] * Bt[Nn][K]^T
// MODE 0: bf16 scatter into qkv[which][b,h,n,hd]; Q (which==0) scaled by QSCALE
// MODE 1: f32 [row][col] + f32 bias   (output projection)
// ---------------------------------------------------------------------------
template <int MODE>
__global__ __launch_bounds__(256, 2)
void gemm128(const unsigned short* __restrict__ A,
             const unsigned short* __restrict__ Bt,
             void* __restrict__ Cv,
             const float* __restrict__ bias,
             int M, int K, int Nn) {
  constexpr int BK = 32;
  __shared__ __align__(16) unsigned short As[128 * BK];
  __shared__ __align__(16) unsigned short Bs[128 * BK];

  const int tid = threadIdx.x;
  const int wave = tid >> 6;
  const int lane = tid & 63;
  const int l15 = lane & 15;
  const int lq = lane >> 4;
  const int row0 = blockIdx.x * 128;
  const int col0 = blockIdx.y * 128;
  const int wr = (wave >> 1) * 64;
  const int wc = (wave & 1) * 64;

  f32x4_t acc[4][4];
#pragma unroll
  for (int m = 0; m < 4; ++m)
#pragma unroll
    for (int n = 0; n < 4; ++n) acc[m][n] = (f32x4_t)0.f;

  const int p0 = tid, p1 = tid + 256;
  const int pr0 = p0 >> 2, ps0 = (p0 & 3) ^ (pr0 & 3);
  const int pr1 = p1 >> 2, ps1 = (p1 & 3) ^ (pr1 & 3);

  char* As0 = (char*)As + wave * 1024;
  char* As1 = (char*)As + 4096 + wave * 1024;
  char* Bs0 = (char*)Bs + wave * 1024;
  char* Bs1 = (char*)Bs + 4096 + wave * 1024;

  const unsigned short* Ap0 = A + (size_t)(row0 + pr0) * K + ps0 * 8;
  const unsigned short* Ap1 = A + (size_t)(row0 + pr1) * K + ps1 * 8;
  const unsigned short* Bp0 = Bt + (size_t)(col0 + pr0) * K + ps0 * 8;
  const unsigned short* Bp1 = Bt + (size_t)(col0 + pr1) * K + ps1 * 8;

  for (int k0 = 0; k0 < K; k0 += BK) {
    __syncthreads();
    gload16(Ap0 + k0, As0);
    gload16(Ap1 + k0, As1);
    gload16(Bp0 + k0, Bs0);
    gload16(Bp1 + k0, Bs1);
    __syncthreads();

    bf16x8_t af[4], bfr[4];
#pragma unroll
    for (int m = 0; m < 4; ++m) {
      int r = wr + m * 16 + l15;
      af[m] = *(const bf16x8_t*)((const char*)As + r * 64 + ((lq ^ (r & 3)) << 4));
    }
#pragma unroll
    for (int n = 0; n < 4; ++n) {
      int c = wc + n * 16 + l15;
      bfr[n] = *(const bf16x8_t*)((const char*)Bs + c * 64 + ((lq ^ (c & 3)) << 4));
    }
#pragma unroll
    for (int m = 0; m < 4; ++m)
#pragma unroll
      for (int n = 0; n < 4; ++n)
        acc[m][n] = __builtin_amdgcn_mfma_f32_16x16x32_bf16(af[m], bfr[n], acc[m][n], 0, 0, 0);
  }

  // C/D layout: col = lane&15, row = (lane>>4)*4 + j  (m89-verified)
#pragma unroll
  for (int m = 0; m < 4; ++m) {
    int rb = row0 + wr + m * 16 + lq * 4;
#pragma unroll
    for (int n = 0; n < 4; ++n) {
      int col = col0 + wc + n * 16 + l15;
#pragma unroll
      for (int j = 0; j < 4; ++j) {
        int row = rb + j;
        float v = acc[m][n][j];
        if constexpr (MODE == 0) {
          int which = col >> 10, cl = col & 1023;
          int b = row >> 11, nn = row & 2047, h = cl >> 6, hd = cl & 63;
          float s = (which == 0) ? QSCALE : 1.0f;
          ((unsigned short*)Cv)[(size_t)which * 8388608 +
                                (((size_t)(b * 16 + h)) * 2048 + nn) * 64 + hd] = f2bf(v * s);
        } else {
          ((float*)Cv)[(size_t)row * Nn + col] = v + bias[col];
        }
      }
    }
  }
}

// ---------------------------------------------------------------------------
// MFMA flash attention, KVBLK=128, double-buffered K/V, 1 barrier/tile.
// qb (pre-scaled by QSCALE), kb: bf16 [bh][2048][64]; vtb: bf16 [bh][64][2048]
// Block: 256 thr = 4 waves; 64 Q rows/block (16/wave).
// ---------------------------------------------------------------------------
__global__ __launch_bounds__(256, 2)
void attn_mfma(const unsigned short* __restrict__ qb,
               const unsigned short* __restrict__ kb,
               const unsigned short* __restrict__ vtb,
               unsigned short* __restrict__ ab) {
  // Ks: [128 key][64 hd], 8 slots/row,  phys = log ^ (key&7)
  // Vs: [64 hd][128 key], 16 slots/row, phys = (s&8)|((s&7)^(hd&7))
  // Ps: per-wave [16 row][128 key], 16 slots/row, phys = (s&8)|((s&7)^(row&7))
  __shared__ __align__(16) unsigned short Ks[2][8192];
  __shared__ __align__(16) unsigned short Vs[2][8192];
  __shared__ __align__(16) unsigned short Ps[4][2048];

  const int tid = threadIdx.x, wave = tid >> 6, lane = tid & 63;
  const int l15 = lane & 15, lq = lane >> 4;
  const int bh = blockIdx.y;
  const int q0 = blockIdx.x * 64;

  const unsigned short* qptr = qb + ((size_t)bh * 2048 + q0 + wave * 16 + l15) * 64;
  bf16x8_t aq0 = *(const bf16x8_t*)(qptr + lq * 8);
  bf16x8_t aq1 = *(const bf16x8_t*)(qptr + 32 + lq * 8);

  f32x4_t O[4];
  float m_run[4], l_run[4];
#pragma unroll
  for (int n = 0; n < 4; ++n) O[n] = (f32x4_t)0.f;
#pragma unroll
  for (int j = 0; j < 4; ++j) { m_run[j] = -1e30f; l_run[j] = 0.f; }

  // staging: 1024 16B chunks each for Ks/Vs per tile; thread stages chunks
  // {tid, tid+256, tid+512, tid+768}. Global source pre-inverse-swizzled.
  const unsigned short* kg[4];
  const unsigned short* vg[4];
#pragma unroll
  for (int i = 0; i < 4; ++i) {
    int c = tid + 256 * i;
    int key = c >> 3, ph = c & 7, lg = ph ^ (key & 7);
    kg[i] = kb + ((size_t)bh * 2048 + key) * 64 + lg * 8;
    int rw = c >> 4, ph2 = c & 15, lg2 = (ph2 & 8) | ((ph2 & 7) ^ (rw & 7));
    vg[i] = vtb + ((size_t)bh * 64 + rw) * 2048 + lg2 * 8;
  }

  // prologue: stage tile 0 into buf 0
#pragma unroll
  for (int i = 0; i < 4; ++i) {
    gload16(kg[i], (char*)Ks[0] + (tid + 256 * i) * 16);
    gload16(vg[i], (char*)Vs[0] + (tid + 256 * i) * 16);
  }
  __syncthreads();  // drains vmcnt(0) before barrier

  char* Pw = (char*)Ps[wave];

  for (int t = 0; t < 16; ++t) {
    const int cur = t & 1;
    if (t < 15) {  // issue next tile's loads into the other buffer
      const size_t koff = (size_t)(t + 1) * 128 * 64;
      const int voff = (t + 1) * 128;
#pragma unroll
      for (int i = 0; i < 4; ++i) {
        gload16(kg[i] + koff, (char*)Ks[cur ^ 1] + (tid + 256 * i) * 16);
        gload16(vg[i] + voff, (char*)Vs[cur ^ 1] + (tid + 256 * i) * 16);
      }
    }

    const char* Kc = (const char*)Ks[cur];
    const char* Vc = (const char*)Vs[cur];

    // S = Q K^T : C col = key (l15 within n-group), row = q (lq*4+j)
    f32x4_t sacc[8];
#pragma unroll
    for (int n = 0; n < 8; ++n) sacc[n] = (f32x4_t)0.f;
#pragma unroll
    for (int ks = 0; ks < 2; ++ks) {
      bf16x8_t aq = ks ? aq1 : aq0;
#pragma unroll
      for (int n = 0; n < 8; ++n) {
        int key = n * 16 + l15;
        bf16x8_t kf = *(const bf16x8_t*)(Kc + key * 128 + (((ks * 4 + lq) ^ (key & 7)) << 4));
        sacc[n] = __builtin_amdgcn_mfma_f32_16x16x32_bf16(aq, kf, sacc[n], 0, 0, 0);
      }
    }

    // online softmax (exp2 domain)
    float mnew[4];
#pragma unroll
    for (int j = 0; j < 4; ++j) {
      float a0 = fmaxf(fmaxf(sacc[0][j], sacc[1][j]), fmaxf(sacc[2][j], sacc[3][j]));
      float a1 = fmaxf(fmaxf(sacc[4][j], sacc[5][j]), fmaxf(sacc[6][j], sacc[7][j]));
      mnew[j] = fmaxf(a0, a1);
    }
#pragma unroll
    for (int mask = 1; mask <= 8; mask <<= 1)
#pragma unroll
      for (int j = 0; j < 4; ++j) mnew[j] = fmaxf(mnew[j], __shfl_xor(mnew[j], mask));

    float alpha[4], psum[4];
#pragma unroll
    for (int j = 0; j < 4; ++j) {
      float mn = fmaxf(m_run[j], mnew[j]);
      alpha[j] = e2(m_run[j] - mn);
      m_run[j] = mn;
      psum[j] = 0.f;
    }

    // P = exp2(S - m); write straight into wave-private LDS (no barrier needed)
#pragma unroll
    for (int n = 0; n < 8; ++n) {
      int slot = n * 2 + (l15 >> 3);
#pragma unroll
      for (int j = 0; j < 4; ++j) {
        float p = e2(sacc[n][j] - m_run[j]);
        psum[j] += p;
        int rowb = lq * 4 + j;
        int phys = (slot & 8) | ((slot & 7) ^ (rowb & 7));
        *(unsigned short*)(Pw + rowb * 256 + phys * 16 + (l15 & 7) * 2) = f2bf(p);
      }
    }
#pragma unroll
    for (int mask = 1; mask <= 8; mask <<= 1)
#pragma unroll
      for (int j = 0; j < 4; ++j) psum[j] += __shfl_xor(psum[j], mask);
#pragma unroll
    for (int j = 0; j < 4; ++j) l_run[j] = l_run[j] * alpha[j] + psum[j];
#pragma unroll
    for (int n = 0; n < 4; ++n)
#pragma unroll
      for (int j = 0; j < 4; ++j) O[n][j] *= alpha[j];

    // O += P V   (A = P[q][k] from Ps, B = V^T cols = hd from Vs)
#pragma unroll
    for (int ks2 = 0; ks2 < 4; ++ks2) {
      int slot = ks2 * 4 + lq;
      int physA = (slot & 8) | ((slot & 7) ^ (l15 & 7));
      bf16x8_t pa = *(const bf16x8_t*)(Pw + l15 * 256 + physA * 16);
#pragma unroll
      for (int n = 0; n < 4; ++n) {
        int hd = n * 16 + l15;
        int physB = (slot & 8) | ((slot & 7) ^ (hd & 7));
        bf16x8_t vf = *(const bf16x8_t*)(Vc + hd * 256 + physB * 16);
        O[n] = __builtin_amdgcn_mfma_f32_16x16x32_bf16(pa, vf, O[n], 0, 0, 0);
      }
    }

    __syncthreads();  // all waves done with buf[cur]; next-tile loads drained
  }

  // epilogue: out row = q0 + wave*16 + lq*4 + j, hd = n*16 + l15
  const int b = bh >> 4, h = bh & 15;
#pragma unroll
  for (int j = 0; j < 4; ++j) {
    float inv = 1.f / l_run[j];
    int row = q0 + wave * 16 + lq * 4 + j;
#pragma unroll
    for (int n = 0; n < 4; ++n)
      ab[((size_t)(b * 2048 + row)) * 1024 + h * 64 + n * 16 + l15] = f2bf(O[n][j] * inv);
  }
}

// ---------------------------------------------------------------------------
extern "C" void kernel_launch(void* const* d_in, const int* in_sizes, int n_in,
                              void* d_out, int out_size, void* d_ws, size_t ws_size,
                              hipStream_t stream) {
  const float* x  = (const float*)d_in[0];
  const float* wq = (const float*)d_in[1];
  const float* wk = (const float*)d_in[2];
  const float* wv = (const float*)d_in[3];
  const float* wo = (const float*)d_in[4];
  const float* bo = (const float*)d_in[5];
  float* out = (float*)d_out;

  const size_t MB = 1ull << 20;
  char* ws = (char*)d_ws;
  unsigned short* xb  = (unsigned short*)(ws);            // 16.8 MB bf16 [8192][1024]
  unsigned short* ab  = xb;                               // reuse after x dead
  unsigned short* qkv = (unsigned short*)(ws + 17 * MB);  // 3 x 16.78 MB [which][bh][2048][64]
  unsigned short* vtb = (unsigned short*)(ws + 68 * MB);  // bf16 [bh][64][2048]
  unsigned short* wT  = (unsigned short*)(ws + 85 * MB);  // 6 MB  [3072][1024]
  unsigned short* woT = (unsigned short*)(ws + 91 * MB);  // 2 MB

  const size_t X = 8388608;  // elems per q/k/v tensor

  const dim3 tb(256);
  f32_to_bf16<<<4096, tb, 0, stream>>>(x, xb);
  transpose_cvt3<<<dim3(32, 32, 3), tb, 0, stream>>>(wq, wk, wv, wT);
  transpose_cvt<<<dim3(32, 32), tb, 0, stream>>>(wo, woT);

  // fused QKV projection: N = 3072
  gemm128<0><<<dim3(64, 24), tb, 0, stream>>>(xb, wT, (void*)qkv, nullptr, 8192, 1024, 3072);

  transpose_v<<<dim3(32, 64), tb, 0, stream>>>(qkv + 2 * X, vtb);

  attn_mfma<<<dim3(32, 64), tb, 0, stream>>>(qkv, qkv + X, vtb, ab);

  gemm128<1><<<dim3(64, 8), tb, 0, stream>>>(ab, woT, (void*)out, bo, 8192, 1024, 1024);
}

// Round 5
// 280.402 us; speedup vs baseline: 1.4809x; 1.3514x over previous
//
#include <hip/hip_runtime.h>
#include <stdint.h>
#include <stddef.h>

typedef __attribute__((ext_vector_type(8))) short bf16x8_t;
typedef __attribute__((ext_vector_type(4))) float f32x4_t;
typedef __attribute__((ext_vector_type(16))) float f32x16_t;
typedef __attribute__((ext_vector_type(4))) unsigned int u32x4_t;
typedef __attribute__((ext_vector_type(2))) unsigned int u32x2_t;

__device__ __forceinline__ unsigned short f2bf(float f) {
  union { float f; unsigned int u; } x; x.f = f;
  unsigned int r = x.u + 0x7fffu + ((x.u >> 16) & 1u);
  return (unsigned short)(r >> 16);
}

__device__ __forceinline__ float e2(float x) { return __builtin_amdgcn_exp2f(x); }

// packed f32x2 -> bf16x2 (RNE), d[15:0]=cvt(lo), d[31:16]=cvt(hi)
__device__ __forceinline__ unsigned int cvtpk(float lo, float hi) {
  unsigned int d;
  asm("v_cvt_pk_bf16_f32 %0, %1, %2" : "=v"(d) : "v"(lo), "v"(hi));
  return d;
}
// after: a = {a.lo-lanes keep, hi-lanes <- b.lo-lanes}, b = {lo-lanes <- a.hi-lanes, hi keep}
__device__ __forceinline__ void plswap(unsigned int& a, unsigned int& b) {
  asm("v_permlane32_swap_b32 %0, %1" : "+v"(a), "+v"(b));
}

// async global->LDS, 16B per lane; LDS dest = wave-uniform base + lane*16
__device__ __forceinline__ void gload16(const void* g, void* l) {
  __builtin_amdgcn_global_load_lds(
      (const __attribute__((address_space(1))) void*)g,
      (__attribute__((address_space(3))) void*)l, 16, 0, 0);
}

// qscale = 1/sqrt(64) * log2(e)  (exp2-domain softmax)
#define QSCALE 0.18033688011112042f

// ---------------------------------------------------------------------------
// x: f32 -> bf16, 8 elems/thread
// ---------------------------------------------------------------------------
__global__ __launch_bounds__(256)
void f32_to_bf16(const float* __restrict__ in, unsigned short* __restrict__ out) {
  size_t i = ((size_t)blockIdx.x * 256 + threadIdx.x) * 8;
  f32x4_t a = *(const f32x4_t*)(in + i);
  f32x4_t b = *(const f32x4_t*)(in + i + 4);
  bf16x8_t o;
#pragma unroll
  for (int j = 0; j < 4; ++j) { o[j] = (short)f2bf(a[j]); o[j + 4] = (short)f2bf(b[j]); }
  *(bf16x8_t*)(out + i) = o;
}

// ---------------------------------------------------------------------------
// 3 weights f32 [1024][1024] -> bf16 transposed, concatenated [3072][1024]
// ---------------------------------------------------------------------------
__global__ __launch_bounds__(256)
void transpose_cvt3(const float* __restrict__ w0, const float* __restrict__ w1,
                    const float* __restrict__ w2, unsigned short* __restrict__ out) {
  __shared__ float t[32][33];
  const float* in = blockIdx.z == 0 ? w0 : (blockIdx.z == 1 ? w1 : w2);
  unsigned short* o = out + (size_t)blockIdx.z * 1024 * 1024;
  const int x = threadIdx.x & 31, y = threadIdx.x >> 5;  // 32 x 8
  const int bx = blockIdx.x * 32, by = blockIdx.y * 32;
#pragma unroll
  for (int i = 0; i < 32; i += 8)
    t[y + i][x] = in[(size_t)(by + y + i) * 1024 + bx + x];
  __syncthreads();
#pragma unroll
  for (int i = 0; i < 32; i += 8)
    o[(size_t)(bx + y + i) * 1024 + by + x] = f2bf(t[x][y + i]);
}

__global__ __launch_bounds__(256)
void transpose_cvt(const float* __restrict__ in, unsigned short* __restrict__ out) {
  __shared__ float t[32][33];
  const int x = threadIdx.x & 31, y = threadIdx.x >> 5;
  const int bx = blockIdx.x * 32, by = blockIdx.y * 32;
#pragma unroll
  for (int i = 0; i < 32; i += 8)
    t[y + i][x] = in[(size_t)(by + y + i) * 1024 + bx + x];
  __syncthreads();
#pragma unroll
  for (int i = 0; i < 32; i += 8)
    out[(size_t)(bx + y + i) * 1024 + by + x] = f2bf(t[x][y + i]);
}

// ---------------------------------------------------------------------------
// v bf16 [bh][2048][64] -> vt bf16 [bh][64][2048]
// ---------------------------------------------------------------------------
__global__ __launch_bounds__(256)
void transpose_v(const unsigned short* __restrict__ in, unsigned short* __restrict__ out) {
  __shared__ unsigned short t[64][65];
  const int bh = blockIdx.y;
  const int n0 = blockIdx.x * 64;
  const int c = threadIdx.x & 63, r4 = threadIdx.x >> 6;  // 64 x 4
#pragma unroll
  for (int i = 0; i < 64; i += 4)
    t[r4 + i][c] = in[((size_t)bh * 2048 + n0 + r4 + i) * 64 + c];
  __syncthreads();
#pragma unroll
  for (int i = 0; i < 64; i += 4)
    out[((size_t)bh * 64 + r4 + i) * 2048 + n0 + c] = t[c][r4 + i];
}

// ---------------------------------------------------------------------------
// 128x128-tile bf16 MFMA GEMM: C = A[M][K] * Bt[Nn][K]^T
// MODE 0: bf16 scatter into qkv[which][b,h,n,hd]; Q (which==0) scaled by QSCALE
// MODE 1: f32 [row][col] + f32 bias   (output projection)
// ---------------------------------------------------------------------------
template <int MODE>
__global__ __launch_bounds__(256, 2)
void gemm128(const unsigned short* __restrict__ A,
             const unsigned short* __restrict__ Bt,
             void* __restrict__ Cv,
             const float* __restrict__ bias,
             int M, int K, int Nn) {
  constexpr int BK = 32;
  __shared__ __align__(16) unsigned short As[128 * BK];
  __shared__ __align__(16) unsigned short Bs[128 * BK];

  const int tid = threadIdx.x;
  const int wave = tid >> 6;
  const int lane = tid & 63;
  const int l15 = lane & 15;
  const int lq = lane >> 4;
  const int row0 = blockIdx.x * 128;
  const int col0 = blockIdx.y * 128;
  const int wr = (wave >> 1) * 64;
  const int wc = (wave & 1) * 64;

  f32x4_t acc[4][4];
#pragma unroll
  for (int m = 0; m < 4; ++m)
#pragma unroll
    for (int n = 0; n < 4; ++n) acc[m][n] = (f32x4_t)0.f;

  const int p0 = tid, p1 = tid + 256;
  const int pr0 = p0 >> 2, ps0 = (p0 & 3) ^ (pr0 & 3);
  const int pr1 = p1 >> 2, ps1 = (p1 & 3) ^ (pr1 & 3);

  char* As0 = (char*)As + wave * 1024;
  char* As1 = (char*)As + 4096 + wave * 1024;
  char* Bs0 = (char*)Bs + wave * 1024;
  char* Bs1 = (char*)Bs + 4096 + wave * 1024;

  const unsigned short* Ap0 = A + (size_t)(row0 + pr0) * K + ps0 * 8;
  const unsigned short* Ap1 = A + (size_t)(row0 + pr1) * K + ps1 * 8;
  const unsigned short* Bp0 = Bt + (size_t)(col0 + pr0) * K + ps0 * 8;
  const unsigned short* Bp1 = Bt + (size_t)(col0 + pr1) * K + ps1 * 8;

  for (int k0 = 0; k0 < K; k0 += BK) {
    __syncthreads();
    gload16(Ap0 + k0, As0);
    gload16(Ap1 + k0, As1);
    gload16(Bp0 + k0, Bs0);
    gload16(Bp1 + k0, Bs1);
    __syncthreads();

    bf16x8_t af[4], bfr[4];
#pragma unroll
    for (int m = 0; m < 4; ++m) {
      int r = wr + m * 16 + l15;
      af[m] = *(const bf16x8_t*)((const char*)As + r * 64 + ((lq ^ (r & 3)) << 4));
    }
#pragma unroll
    for (int n = 0; n < 4; ++n) {
      int c = wc + n * 16 + l15;
      bfr[n] = *(const bf16x8_t*)((const char*)Bs + c * 64 + ((lq ^ (c & 3)) << 4));
    }
#pragma unroll
    for (int m = 0; m < 4; ++m)
#pragma unroll
      for (int n = 0; n < 4; ++n)
        acc[m][n] = __builtin_amdgcn_mfma_f32_16x16x32_bf16(af[m], bfr[n], acc[m][n], 0, 0, 0);
  }

  // C/D layout: col = lane&15, row = (lane>>4)*4 + j  (m89-verified)
#pragma unroll
  for (int m = 0; m < 4; ++m) {
    int rb = row0 + wr + m * 16 + lq * 4;
#pragma unroll
    for (int n = 0; n < 4; ++n) {
      int col = col0 + wc + n * 16 + l15;
#pragma unroll
      for (int j = 0; j < 4; ++j) {
        int row = rb + j;
        float v = acc[m][n][j];
        if constexpr (MODE == 0) {
          int which = col >> 10, cl = col & 1023;
          int b = row >> 11, nn = row & 2047, h = cl >> 6, hd = cl & 63;
          float s = (which == 0) ? QSCALE : 1.0f;
          ((unsigned short*)Cv)[(size_t)which * 8388608 +
                                (((size_t)(b * 16 + h)) * 2048 + nn) * 64 + hd] = f2bf(v * s);
        } else {
          ((float*)Cv)[(size_t)row * Nn + col] = v + bias[col];
        }
      }
    }
  }
}

// ---------------------------------------------------------------------------
// MFMA flash attention, 32x32x16 fragments, swapped operands, in-register P.
// qb (pre-scaled by QSCALE), kb: bf16 [bh][2048][64]; vtb: bf16 [bh][64][2048]
// Block: 256 thr = 4 waves; 128 q-rows/block (32/wave); KVBLK=128, dbuf.
// Grid: 1024 blocks 1D, XCD-swizzled so each bh's 16 q-blocks share an XCD.
// ---------------------------------------------------------------------------
__global__ __launch_bounds__(256, 2)
void attn_mfma(const unsigned short* __restrict__ qb,
               const unsigned short* __restrict__ kb,
               const unsigned short* __restrict__ vtb,
               unsigned short* __restrict__ ab) {
  // Ks: [128 key][8 slots x 8 hd], phys = slot ^ (key&7)
  // Vs: [64 hd][16 slots x 8 key], phys = (s&8)|((s&7)^(hd&7))
  __shared__ __align__(16) unsigned short Ks[2][8192];
  __shared__ __align__(16) unsigned short Vs[2][8192];

  const int tid = threadIdx.x, wave = tid >> 6, lane = tid & 63;
  const int l31 = lane & 31, hi = lane >> 5;

  // XCD swizzle: linear dispatch -> xcd = bid & 7 (8 XCDs)
  const int bid = blockIdx.x;
  const int xcd = bid & 7, w = bid >> 3;
  const int bh = xcd * 8 + (w >> 4);
  const int q0 = (w & 15) * 128;

  // Q as B-fragments: col = q = l31, k = hi*8 + j; 4 k-steps over hd
  const unsigned short* qrow = qb + ((size_t)bh * 2048 + q0 + wave * 32 + l31) * 64;
  bf16x8_t qf[4];
#pragma unroll
  for (int ks = 0; ks < 4; ++ks)
    qf[ks] = *(const bf16x8_t*)(qrow + ks * 16 + hi * 8);

  f32x16_t O[2];
#pragma unroll
  for (int hb = 0; hb < 2; ++hb) O[hb] = (f32x16_t)0.f;
  float m_run = -1e30f, l_run = 0.f;

  // staging offsets (elements), inverse-swizzled global sources
  const unsigned short* kbase = kb + (size_t)bh * 2048 * 64;
  const unsigned short* vbase = vtb + (size_t)bh * 64 * 2048;
  int koff[4], voff[4];
#pragma unroll
  for (int i = 0; i < 4; ++i) {
    int c = tid + 256 * i;
    int kr = c >> 3, kp = c & 7, kl = kp ^ (kr & 7);
    koff[i] = kr * 64 + kl * 8;
    int vr = c >> 4, vp = c & 15, vl = (vp & 8) | ((vp & 7) ^ (vr & 7));
    voff[i] = vr * 2048 + vl * 8;
  }

  // prologue: stage tile 0 into buf 0
#pragma unroll
  for (int i = 0; i < 4; ++i) {
    gload16(kbase + koff[i], (char*)Ks[0] + (tid + 256 * i) * 16);
    gload16(vbase + voff[i], (char*)Vs[0] + (tid + 256 * i) * 16);
  }
  __syncthreads();

  for (int t = 0; t < 16; ++t) {
    const int cur = t & 1;
    if (t < 15) {
      const unsigned short* kt = kbase + (size_t)(t + 1) * 8192;
      const unsigned short* vt = vbase + (t + 1) * 128;
#pragma unroll
      for (int i = 0; i < 4; ++i) {
        gload16(kt + koff[i], (char*)Ks[cur ^ 1] + (tid + 256 * i) * 16);
        gload16(vt + voff[i], (char*)Vs[cur ^ 1] + (tid + 256 * i) * 16);
      }
    }
    const char* Kc = (const char*)Ks[cur];
    const char* Vc = (const char*)Vs[cur];

    // S = K Q : C col = q (l31), row-in-block = (reg&3) + 8*(reg>>2) + 4*hi
    f32x16_t sacc[4];
#pragma unroll
    for (int kbk = 0; kbk < 4; ++kbk) sacc[kbk] = (f32x16_t)0.f;
#pragma unroll
    for (int kbk = 0; kbk < 4; ++kbk) {
#pragma unroll
      for (int ks = 0; ks < 4; ++ks) {
        int key = kbk * 32 + l31;
        bf16x8_t kf = *(const bf16x8_t*)(Kc + key * 128 + (((ks * 2 + hi) ^ (key & 7)) << 4));
        sacc[kbk] = __builtin_amdgcn_mfma_f32_32x32x16_bf16(kf, qf[ks], sacc[kbk], 0, 0, 0);
      }
    }

    // online softmax (exp2 domain); per-lane state for q-row = l31
    float mx = -1e30f;
#pragma unroll
    for (int kbk = 0; kbk < 4; ++kbk)
#pragma unroll
      for (int r = 0; r < 16; ++r) mx = fmaxf(mx, sacc[kbk][r]);
    mx = fmaxf(mx, __shfl_xor(mx, 32));

    const float mn = fmaxf(m_run, mx);
    const float alpha = e2(m_run - mn);
    m_run = mn;
#pragma unroll
    for (int hb = 0; hb < 2; ++hb)
#pragma unroll
      for (int r = 0; r < 16; ++r) O[hb][r] *= alpha;

    float psum = 0.f;
#pragma unroll
    for (int kbk = 0; kbk < 4; ++kbk) {
      float p[16];
#pragma unroll
      for (int r = 0; r < 16; ++r) {
        p[r] = e2(sacc[kbk][r] - mn);
        psum += p[r];
      }
      // P -> PV B-fragments via cvt_pk + permlane32_swap (T12)
#pragma unroll
      for (int u = 0; u < 2; ++u) {
        unsigned int a0 = cvtpk(p[8 * u + 0], p[8 * u + 1]);
        unsigned int b0 = cvtpk(p[8 * u + 4], p[8 * u + 5]);
        plswap(a0, b0);  // a0 = dword0, b0 = dword2
        unsigned int a1 = cvtpk(p[8 * u + 2], p[8 * u + 3]);
        unsigned int b1 = cvtpk(p[8 * u + 6], p[8 * u + 7]);
        plswap(a1, b1);  // a1 = dword1, b1 = dword3
        u32x4_t fw; fw[0] = a0; fw[1] = a1; fw[2] = b0; fw[3] = b1;
        bf16x8_t pfrag = *(bf16x8_t*)&fw;
        const int ks2 = kbk * 2 + u;
#pragma unroll
        for (int hb = 0; hb < 2; ++hb) {
          int hd = hb * 32 + l31;
          int sl = ks2 * 2 + hi;
          bf16x8_t vf = *(const bf16x8_t*)(Vc + hd * 256 +
                          (((sl & 8) | ((sl & 7) ^ (hd & 7))) << 4));
          O[hb] = __builtin_amdgcn_mfma_f32_32x32x16_bf16(vf, pfrag, O[hb], 0, 0, 0);
        }
      }
    }
    psum += __shfl_xor(psum, 32);
    l_run = l_run * alpha + psum;

    __syncthreads();
  }

  // epilogue: O col = q = l31; row = hd-in-block = (reg&3) + 8*(reg>>2) + 4*hi
  const int b = bh >> 4, h = bh & 15;
  const float inv = 1.f / l_run;
  const int row = q0 + wave * 32 + l31;
  unsigned short* op = ab + ((size_t)(b * 2048 + row)) * 1024 + h * 64;
#pragma unroll
  for (int hb = 0; hb < 2; ++hb)
#pragma unroll
    for (int tt = 0; tt < 4; ++tt) {
      u32x2_t d;
      d[0] = cvtpk(O[hb][4 * tt + 0] * inv, O[hb][4 * tt + 1] * inv);
      d[1] = cvtpk(O[hb][4 * tt + 2] * inv, O[hb][4 * tt + 3] * inv);
      *(u32x2_t*)(op + hb * 32 + tt * 8 + hi * 4) = d;
    }
}

// ---------------------------------------------------------------------------
extern "C" void kernel_launch(void* const* d_in, const int* in_sizes, int n_in,
                              void* d_out, int out_size, void* d_ws, size_t ws_size,
                              hipStream_t stream) {
  const float* x  = (const float*)d_in[0];
  const float* wq = (const float*)d_in[1];
  const float* wk = (const float*)d_in[2];
  const float* wv = (const float*)d_in[3];
  const float* wo = (const float*)d_in[4];
  const float* bo = (const float*)d_in[5];
  float* out = (float*)d_out;

  const size_t MB = 1ull << 20;
  char* ws = (char*)d_ws;
  unsigned short* xb  = (unsigned short*)(ws);            // 16.8 MB bf16 [8192][1024]
  unsigned short* ab  = xb;                               // reuse after x dead
  unsigned short* qkv = (unsigned short*)(ws + 17 * MB);  // 3 x 16.78 MB
  unsigned short* vtb = (unsigned short*)(ws + 68 * MB);  // bf16 [bh][64][2048]
  unsigned short* wT  = (unsigned short*)(ws + 85 * MB);  // 6 MB  [3072][1024]
  unsigned short* woT = (unsigned short*)(ws + 91 * MB);  // 2 MB

  const size_t X = 8388608;  // elems per q/k/v tensor

  const dim3 tb(256);
  f32_to_bf16<<<4096, tb, 0, stream>>>(x, xb);
  transpose_cvt3<<<dim3(32, 32, 3), tb, 0, stream>>>(wq, wk, wv, wT);
  transpose_cvt<<<dim3(32, 32), tb, 0, stream>>>(wo, woT);

  // fused QKV projection: N = 3072
  gemm128<0><<<dim3(64, 24), tb, 0, stream>>>(xb, wT, (void*)qkv, nullptr, 8192, 1024, 3072);

  transpose_v<<<dim3(32, 64), tb, 0, stream>>>(qkv + 2 * X, vtb);

  attn_mfma<<<dim3(1024), tb, 0, stream>>>(qkv, qkv + X, vtb, ab);

  gemm128<1><<<dim3(64, 8), tb, 0, stream>>>(ab, woT, (void*)out, bo, 8192, 1024, 1024);
}